// Round 3
// baseline (234.249 us; speedup 1.0000x reference)
//
#include <hip/hip_runtime.h>
#include <stdint.h>

// All buffers f32. Timed window carries ~165 us of harness poison fills
// (857 MB ws fill @ ~132 us + 219 MB out fill @ ~33 us, visible in rocprof
// every iteration); our dispatches are the ~64 us remainder.
// Config history: r5 plain/CSPLIT4 = 231.0 | r4 = 233.6 | r7 nt/CSPLIT2 = 240.2
//   r8 branchless zero-row gather = 229.5 (neutral -> not load-latency-bound)
//   r9 channel-split inside block  = 229.1 (neutral -> not XCD-read-replication)
// r10: (a) drop the canvas memset dispatch — gather SELF-VALIDATES canvas
// entries by round-tripping through coords (sound for ANY ws poison value:
// a garbage q that maps back to this cell implies pillar q truly occupies it,
// in which case scatter wrote the same value). (b) bijective XCD-chunked
// block swizzle on the gather so each XCD writes contiguous spatial runs
// per plane instead of 1KB@8KB-stride interleave (DRAM row locality for the
// 219 MB store stream).
#define NYv 496
#define NXv 432
#define Cv  64
#define Bv  4
#define PLANE (NYv * NXv)            // 214272 elements per (b,c) plane
#define NVEC (NXv / 4)               // 108 float4 vectors per canvas row
#define ROWS (Bv * NYv)              // 1984 canvas rows
#define UNITS (ROWS * NVEC)          // 214272 vec-units == 3348 * 64 exactly
#define CSPLIT 4                     // c-chunks = waves per block
#define CCHUNK (Cv / CSPLIT)         // 16 channels per gather thread
#define CANVAS_INTS (Bv * PLANE)     // 857088 ints = 3.43 MB
#define NBLK (UNITS / 64)            // 3348 gather blocks
#define SWZ 1                        // XCD-chunked block swizzle toggle
#define XQ (NBLK / 8)                // 418
#define XR (NBLK % 8)                // 4

typedef float  f32x4 __attribute__((ext_vector_type(4)));
typedef int    i32x4 __attribute__((ext_vector_type(4)));

// K1: scatter pillar index i into canvas[(b*NY + y)*NX + x].
// No canvas init needed — gather validates entries via coords round-trip.
// Also re-zeroes the 64-float zero-row (ws is poisoned every iter).
__global__ __launch_bounds__(256) void scatter_idx(const int4* __restrict__ coords,
                                                   int* __restrict__ canvas,
                                                   float* __restrict__ zerorow, int n) {
    int i = blockIdx.x * 256 + threadIdx.x;
    if (i < Cv) zerorow[i] = 0.0f;     // block 0 refreshes the zero row
    if (i >= n) return;
    int4 c4 = coords[i];               // (b, z, y, x)
    canvas[((size_t)c4.x * NYv + c4.z) * NXv + c4.w] = i;
}

// K2: inverse gather, exact cover: 3348 blocks x 64 lanes == 214272 units,
// 4 waves/block == 4 channel-chunks. Per thread: one int4 canvas load ->
// 4 candidate pillar indices; each validated by round-trip through coords
// (in-range AND maps back to this exact cell). Valid -> feature row base,
// invalid -> L1-resident zero row. 16 unconditional f32x4 loads register-
// transposed into 16 coalesced float4 plane stores.
__global__ __launch_bounds__(256) void gather_all(const float* __restrict__ feats,
                                                  const int* __restrict__ canvas,
                                                  const int4* __restrict__ coords,
                                                  const float* __restrict__ zerorow,
                                                  float* __restrict__ out, int n) {
#if SWZ
    // Bijective XCD chunking (m204): xcd = orig%8 owns a contiguous block range.
    int orig = (int)blockIdx.x;
    int xcd = orig & 7, off = orig >> 3;
    int blk = (xcd < XR ? xcd * (XQ + 1) : XR * (XQ + 1) + (xcd - XR) * XQ) + off;
#else
    int blk = (int)blockIdx.x;
#endif
    int lane = (int)threadIdx.x & 63;
    int u = blk * 64 + lane;                       // 0..214271 (spatial vec-unit)
    int c0 = ((int)threadIdx.x >> 6) * CCHUNK;     // wave id -> channel chunk
    int g = u / NVEC;                              // canvas row 0..1983
    int v = u - g * NVEC;                          // 0..107
    int b = g / NYv;
    int y = g - b * NYv;
    int cellbase = g * NXv + v * 4;                // canvas linear index of slot 0

    i32x4 pi = *reinterpret_cast<const i32x4*>(canvas + (size_t)cellbase);
    int p[4] = {pi.x, pi.y, pi.z, pi.w};

    // Self-validating base select: accept q only if coords[q] round-trips to
    // this cell. Empty cells (any poison) fail and read the zero row.
    const float* base[4];
#pragma unroll
    for (int j = 0; j < 4; ++j) {
        const float* bp = zerorow;
        int q = p[j];
        if ((unsigned)q < (unsigned)n) {           // exec-masked validate load
            int4 cq = coords[q];
            if ((cq.x * NYv + cq.z) * NXv + cq.w == cellbase + j)
                bp = feats + (size_t)q * Cv;
        }
        base[j] = bp + c0;
    }

    // One unconditional load cluster: 16 outstanding dwordx4 per thread.
    f32x4 w[4][4];
#pragma unroll
    for (int cg = 0; cg < CCHUNK / 4; ++cg)
#pragma unroll
        for (int j = 0; j < 4; ++j)
            w[cg][j] = *reinterpret_cast<const f32x4*>(base[j] + cg * 4);

    float* outp = out + ((size_t)(b * Cv + c0)) * PLANE + y * NXv + v * 4;
#pragma unroll
    for (int cg = 0; cg < CCHUNK / 4; ++cg) {
#pragma unroll
        for (int k = 0; k < 4; ++k) {              // transpose: channel k of group
            f32x4 f;
            f.x = w[cg][0][k]; f.y = w[cg][1][k];
            f.z = w[cg][2][k]; f.w = w[cg][3][k];
            *reinterpret_cast<f32x4*>(outp + (size_t)(cg * 4 + k) * PLANE) = f;
        }
    }
}

extern "C" void kernel_launch(void* const* d_in, const int* in_sizes, int n_in,
                              void* d_out, int out_size, void* d_ws, size_t ws_size,
                              hipStream_t stream) {
    const float* feats  = (const float*)d_in[0];   // f32, [N, 64]
    const int*   coords = (const int*)d_in[1];     // int32, [N, 4]
    int n = in_sizes[0] / Cv;                      // 48000 pillars
    float* out    = (float*)d_out;
    int*   canvas = (int*)d_ws;                    // 3.43 MB of ~877 MB ws
    float* zerorow = (float*)((char*)d_ws + (size_t)CANVAS_INTS * sizeof(int));
    // zerorow offset 3,428,352 B — 16B-aligned.

    // No canvas memset: gather self-validates entries (correct for any poison).
    scatter_idx<<<(n + 255) / 256, 256, 0, stream>>>((const int4*)coords, canvas,
                                                     zerorow, n);

    gather_all<<<NBLK, 256, 0, stream>>>(feats, canvas, (const int4*)coords,
                                         zerorow, out, n);
}

// Round 4
// 230.813 us; speedup vs baseline: 1.0149x; 1.0149x over previous
//
#include <hip/hip_runtime.h>
#include <stdint.h>

// All buffers f32. Timed window carries ~165 us of harness poison fills
// (857 MB ws fill @ ~132 us + 219 MB out fill @ ~33 us, visible in rocprof
// every iteration); our 3 dispatches are the ~64 us remainder.
// Config history: r5 plain/CSPLIT4 = 231.0 | r4 = 233.6 | r7 nt/CSPLIT2 = 240.2
//   r8 branchless zero-row gather = 229.5 (neutral -> not load-latency-bound)
//   r9 channel-split inside block = 229.1 (neutral -> not XCD-read-replication)
//   r10 memset-elim via coords round-trip validation + XCD swizzle = 234.2
//       (REGRESSED: dependent validate-load chain before the feature cluster
//        + ~3% slower machine that round; reverted)
// r11: exact r9 revert — the measured optimum. Remaining slack (~15 us of
// gather over its DMA floor) has resisted 5 distinct mechanisms (nt stores,
// branchless loads, wave-level channel clustering, dispatch elimination,
// XCD swizzle); attributed to mixed R/W HBM stream turnaround.
#define NYv 496
#define NXv 432
#define Cv  64
#define Bv  4
#define PLANE (NYv * NXv)            // 214272 elements per (b,c) plane
#define NVEC (NXv / 4)               // 108 float4 vectors per canvas row
#define ROWS (Bv * NYv)              // 1984 canvas rows
#define UNITS (ROWS * NVEC)          // 214272 vec-units == 3348 * 64 exactly
#define CSPLIT 4                     // c-chunks = waves per block
#define CCHUNK (Cv / CSPLIT)         // 16 channels per gather thread
#define CANVAS_INTS (Bv * PLANE)     // 857088 ints = 3.43 MB

typedef float  f32x4 __attribute__((ext_vector_type(4)));
typedef int    i32x4 __attribute__((ext_vector_type(4)));

// K1: scatter pillar index i into canvas[(b*NY + y)*NX + x].
// Canvas pre-set to -1 (memset 0xFF) so unoccupied cells read <0.
// Also re-zeroes the 64-float zero-row (ws is poisoned every iter).
__global__ __launch_bounds__(256) void scatter_idx(const int4* __restrict__ coords,
                                                   int* __restrict__ canvas,
                                                   float* __restrict__ zerorow, int n) {
    int i = blockIdx.x * 256 + threadIdx.x;
    if (i < Cv) zerorow[i] = 0.0f;     // block 0 refreshes the zero row
    if (i >= n) return;
    int4 c4 = coords[i];               // (b, z, y, x)
    canvas[((size_t)c4.x * NYv + c4.z) * NXv + c4.w] = i;
}

// K2: inverse gather, exact cover: 3348 blocks x 64 lanes == 214272 units,
// 4 waves/block == 4 channel-chunks. Per thread: one int4 canvas load ->
// 4 pillar indices; branchless base-pointer select (empty -> L1-resident
// zero row); 16 unconditional f32x4 loads register-transposed into 16
// coalesced float4 plane stores (1 KB contiguous per wave-store — maximal
// without LDS staging, which would need >=128 KB and crater occupancy).
__global__ __launch_bounds__(256) void gather_all(const float* __restrict__ feats,
                                                  const int* __restrict__ canvas,
                                                  const float* __restrict__ zerorow,
                                                  float* __restrict__ out) {
    int lane = (int)threadIdx.x & 63;
    int u = blockIdx.x * 64 + lane;                // 0..214271 (spatial vec-unit)
    int c0 = ((int)threadIdx.x >> 6) * CCHUNK;     // wave id -> channel chunk
    int g = u / NVEC;                              // canvas row 0..1983
    int v = u - g * NVEC;                          // 0..107
    int b = g / NYv;
    int y = g - b * NYv;

    i32x4 pi = *reinterpret_cast<const i32x4*>(canvas + (size_t)g * NXv + v * 4);
    int p[4] = {pi.x, pi.y, pi.z, pi.w};

    // Branchless base select: empty cells read the zero row (64 zero floats,
    // always cache-hit). c0 + cg*4 + 4 <= 64, so zerorow + c0 stays in bounds.
    const float* base[4];
#pragma unroll
    for (int j = 0; j < 4; ++j)
        base[j] = ((p[j] >= 0) ? (feats + (size_t)p[j] * Cv) : zerorow) + c0;

    // One unconditional load cluster: 16 outstanding dwordx4 per thread.
    f32x4 w[4][4];
#pragma unroll
    for (int cg = 0; cg < CCHUNK / 4; ++cg)
#pragma unroll
        for (int j = 0; j < 4; ++j)
            w[cg][j] = *reinterpret_cast<const f32x4*>(base[j] + cg * 4);

    float* outp = out + ((size_t)(b * Cv + c0)) * PLANE + y * NXv + v * 4;
#pragma unroll
    for (int cg = 0; cg < CCHUNK / 4; ++cg) {
#pragma unroll
        for (int k = 0; k < 4; ++k) {              // transpose: channel k of group
            f32x4 f;
            f.x = w[cg][0][k]; f.y = w[cg][1][k];
            f.z = w[cg][2][k]; f.w = w[cg][3][k];
            *reinterpret_cast<f32x4*>(outp + (size_t)(cg * 4 + k) * PLANE) = f;
        }
    }
}

extern "C" void kernel_launch(void* const* d_in, const int* in_sizes, int n_in,
                              void* d_out, int out_size, void* d_ws, size_t ws_size,
                              hipStream_t stream) {
    const float* feats  = (const float*)d_in[0];   // f32, [N, 64]
    const int*   coords = (const int*)d_in[1];     // int32, [N, 4]
    int n = in_sizes[0] / Cv;                      // 48000 pillars
    float* out    = (float*)d_out;
    int*   canvas = (int*)d_ws;                    // 3.43 MB of ~877 MB ws
    float* zerorow = (float*)((char*)d_ws + (size_t)CANVAS_INTS * sizeof(int));
    // zerorow offset 3,428,352 B — 16B-aligned.

    // -1 sentinel (0xAA poison is also negative, but don't rely on it).
    (void)hipMemsetAsync(canvas, 0xFF, (size_t)CANVAS_INTS * sizeof(int), stream);

    scatter_idx<<<(n + 255) / 256, 256, 0, stream>>>((const int4*)coords, canvas,
                                                     zerorow, n);

    gather_all<<<UNITS / 64, 256, 0, stream>>>(feats, canvas, zerorow, out);
}